// Round 2
// baseline (41756.989 us; speedup 1.0000x reference)
//
#include <hip/hip_runtime.h>

// RNNEncModel: embed -> MLP(relu x2) -> 2x bidirectional tanh-RNN -> final states [4,64,1024] f32.
// B=64 T=512 E=512 H=1024 V=32000.
// fp16 compute (f32 MFMA accum). Input projections FUSED into the persistent scan kernels
// (computed before the per-step flag wait -> hidden under sync latency). ws NEED = 196 MB.

typedef _Float16 f16;
typedef _Float16 f16x8 __attribute__((ext_vector_type(8)));
typedef _Float16 f16x4 __attribute__((ext_vector_type(4)));
typedef float f32x4 __attribute__((ext_vector_type(4)));

static const size_t MB_ = 1024ull * 1024ull;
static const size_t OFF_X0    = 0;                      // [512*64][1024] f16 = 64MB (MLP out, [t][b][h])
static const size_t OFF_X1    = 64 * MB_;               // [512*64][2048] f16 = 128MB (layer0 out, [t][b][dir*H+h])
static const size_t OFF_EMB   = OFF_X1;                 // tmp [32768][512] f16 = 32MB (dead before X1 written)
static const size_t OFF_MLP1  = 96 * MB_;               // tmp [32768][1024] f16 = 64MB (dead before X1 written)
static const size_t OFF_H     = 192 * MB_;              // [2dir][2buf][64][1024] f16 = 512KB
static const size_t OFF_FLAGS = 192 * MB_ + 512 * 1024; // [2dir][2bg][64cg] u32 = 1KB
static const size_t OFF_BIAS  = 192 * MB_ + 576 * 1024; // [4][1024] f32 (b_ih + b_hh)
static const size_t OFF_W1C   = 193 * MB_;              // W1 f16 [1024][512] = 1MB
static const size_t OFF_W2C   = 194 * MB_;              // W2 f16 [1024][1024] = 2MB
static const size_t WS_NEED   = 196 * MB_;

__device__ __forceinline__ void gld16(const void* g, void* l) {
#if __has_builtin(__builtin_amdgcn_global_load_lds)
  __builtin_amdgcn_global_load_lds((const __attribute__((address_space(1))) void*)g,
                                   (__attribute__((address_space(3))) void*)l, 16, 0, 0);
#else
  *(f16x8*)l = *(const f16x8*)g;
#endif
}

// ---------------- utility kernels ----------------

__global__ void zero_k(unsigned int* __restrict__ p, int n) {
  int i = blockIdx.x * blockDim.x + threadIdx.x;
  if (i < n) p[i] = 0u;
}

__global__ void cvt_k(const float* __restrict__ in, f16* __restrict__ out, int n4) {
  int i = blockIdx.x * blockDim.x + threadIdx.x;
  int stride = gridDim.x * blockDim.x;
  for (; i < n4; i += stride) {
    float4 v = ((const float4*)in)[i];
    f16x4 o = {(f16)v.x, (f16)v.y, (f16)v.z, (f16)v.w};
    ((f16x4*)out)[i] = o;
  }
}

__global__ void bias_k(const float* __restrict__ a, const float* __restrict__ b, float* __restrict__ o) {
  int i = blockIdx.x * blockDim.x + threadIdx.x;
  if (i < 4096) o[i] = a[i] + b[i];
}

// embedding gather + f16 convert; padding_idx=0 -> zero row
__global__ void embed_k(const int* __restrict__ src, const float* __restrict__ tab, f16* __restrict__ out) {
  int m = blockIdx.x;     // token index b*512 + t
  int tid = threadIdx.x;  // 128 threads x 4 floats
  int tok = src[m];
  f16x4 o = {(f16)0.f, (f16)0.f, (f16)0.f, (f16)0.f};
  if (tok != 0) {
    float4 v = *(const float4*)(tab + (size_t)tok * 512 + tid * 4);
    o[0] = (f16)v.x; o[1] = (f16)v.y; o[2] = (f16)v.z; o[3] = (f16)v.w;
  }
  *(f16x4*)(out + (size_t)m * 512 + tid * 4) = o;
}

// ---------------- GEMM: C[M,N] = A[M,K(lda)] * Bw[N,K]^T ----------------
// EPI bit0: relu(acc + bias[col]); EPI bit1: scatter row=(b*512+t) -> out[(t*64+b)*1024+col] (N==1024)
template <int EPI>
__global__ __launch_bounds__(256) void gemm_f16(
    const f16* __restrict__ A, int lda, const f16* __restrict__ Bw,
    f16* __restrict__ out, const float* __restrict__ bias, int M, int N, int K) {
  __shared__ alignas(16) f16 As[4096];  // [128][32]
  __shared__ alignas(16) f16 Bs[4096];  // [128][32]
  const int nt = N >> 7;
  const int bx = blockIdx.x;
  const int tm = bx / nt, tn = bx - tm * nt;
  const int tid = threadIdx.x;
  const int l = tid & 63, w = tid >> 6;
  const int wr = w >> 1, wc = w & 1;
  const int srow = (w << 4) + (l >> 2);
  const int scol = (l & 3) << 3;
  const f16* Ab = A + (size_t)(tm * 128 + srow) * lda + scol;
  const f16* Bb = Bw + (size_t)(tn * 128 + srow) * K + scol;
  f32x4 acc[4][4];
#pragma unroll
  for (int i = 0; i < 4; i++)
#pragma unroll
    for (int j = 0; j < 4; j++) acc[i][j] = (f32x4){0.f, 0.f, 0.f, 0.f};
  const int ar = l & 15, ak = (l >> 4) << 3;
  for (int k0 = 0; k0 < K; k0 += 32) {
    gld16(Ab + k0, &As[tid * 8]);
    gld16(Ab + (size_t)64 * lda + k0, &As[tid * 8 + 2048]);
    gld16(Bb + k0, &Bs[tid * 8]);
    gld16(Bb + (size_t)64 * K + k0, &Bs[tid * 8 + 2048]);
    __syncthreads();
    f16x8 av[4], bv[4];
#pragma unroll
    for (int i = 0; i < 4; i++) av[i] = *(const f16x8*)&As[(wr * 64 + i * 16 + ar) * 32 + ak];
#pragma unroll
    for (int j = 0; j < 4; j++) bv[j] = *(const f16x8*)&Bs[(wc * 64 + j * 16 + ar) * 32 + ak];
#pragma unroll
    for (int i = 0; i < 4; i++)
#pragma unroll
      for (int j = 0; j < 4; j++)
        acc[i][j] = __builtin_amdgcn_mfma_f32_16x16x32_f16(av[i], bv[j], acc[i][j], 0, 0, 0);
    __syncthreads();
  }
  const int r0 = (l >> 4) << 2, c0 = l & 15;
#pragma unroll
  for (int i = 0; i < 4; i++) {
#pragma unroll
    for (int j = 0; j < 4; j++) {
      const int col = tn * 128 + wc * 64 + j * 16 + c0;
      const float bc = (EPI & 1) ? bias[col] : 0.f;
#pragma unroll
      for (int r = 0; r < 4; r++) {
        const int row = tm * 128 + wr * 64 + i * 16 + r0 + r;
        float v = acc[i][j][r];
        if (EPI & 1) { v += bc; v = v > 0.f ? v : 0.f; }
        if (EPI & 2) {
          const int b_ = row >> 9, t = row & 511;
          out[((size_t)(t * 64 + b_) << 10) + col] = (f16)v;
        } else {
          out[(size_t)row * N + col] = (f16)v;
        }
      }
    }
  }
}

// ---------------- fused recurrence ----------------
// grid 256 = dir(2) x bg(2, 32 batch rows) x cg(64, 16 cols). 4 waves: (mi batch-half, kh K-half).
// Per step: h_new = tanh(x[t]@Wih^T + h@Whh^T + bias). Wih & Whh slices f16 in LDS (XOR-swizzled).
// x-projection computed BEFORE the flag wait (no dependency) -> hides under sync latency.
// Sync: flags[dir][bg][cg] = monotonic epoch; relaxed agent spin + threadfence acquire/release.
template <int LAYER>
__global__ __launch_bounds__(256) void rnn_scan(
    const f16* __restrict__ X,       // [512*64][KX]  (t-major)
    const float* __restrict__ Wih,   // [2][1024][KX] f32
    const float* __restrict__ Whh,   // [2][2][1024][1024] f32
    const float* __restrict__ bsum,  // [4][1024]
    f16* __restrict__ hbuf,          // [2][2][64][1024] f16
    unsigned int* __restrict__ flags,// [2][2][64] u32
    f16* __restrict__ seqout,        // LAYER0: [512*64][2048]
    float* __restrict__ dout) {      // [4][64][1024]
  constexpr int KX = LAYER ? 2048 : 1024;
  constexpr int XSH = LAYER ? 11 : 10;
  const int bid = blockIdx.x;
  const int dir = bid >> 7, bg = (bid >> 6) & 1, cg = bid & 63;
  const int tid = threadIdx.x, l = tid & 63, w = tid >> 6;
  const int mi = w & 1, kh = w >> 1;
  __shared__ alignas(16) f16 Wl[16 * 1024];   // Whh slice
  __shared__ alignas(16) f16 Wi[16 * KX];     // Wih slice
  __shared__ float part[2][16][16];
  const int ld = LAYER * 2 + dir;
  // stage Whh slice (16 out-cols x 1024) f32 -> f16, XOR swizzle (k0 ^= (n&7)<<3)
  for (int ch = tid; ch < 2048; ch += 256) {
    const int n = ch >> 7, k0 = (ch & 127) << 3;
    const float* wp = Whh + (((size_t)(ld * 1024 + cg * 16 + n)) << 10) + k0;
    float4 v0 = *(const float4*)wp, v1 = *(const float4*)(wp + 4);
    f16x8 hv = {(f16)v0.x, (f16)v0.y, (f16)v0.z, (f16)v0.w,
                (f16)v1.x, (f16)v1.y, (f16)v1.z, (f16)v1.w};
    *(f16x8*)&Wl[(n << 10) + (k0 ^ ((n & 7) << 3))] = hv;
  }
  // stage Wih slice (16 out-cols x KX) f32 -> f16, same swizzle
  for (int ch = tid; ch < (16 * KX / 8); ch += 256) {
    const int n = ch >> (XSH - 3), k0 = (ch & (KX / 8 - 1)) << 3;
    const float* wp = Wih + ((size_t)(dir * 1024 + cg * 16 + n)) * KX + k0;
    float4 v0 = *(const float4*)wp, v1 = *(const float4*)(wp + 4);
    f16x8 hv = {(f16)v0.x, (f16)v0.y, (f16)v0.z, (f16)v0.w,
                (f16)v1.x, (f16)v1.y, (f16)v1.z, (f16)v1.w};
    *(f16x8*)&Wi[(n << XSH) + (k0 ^ ((n & 7) << 3))] = hv;
  }
  const float bn = bsum[(ld << 10) + cg * 16 + (l & 15)];
  f16* hD = hbuf + ((size_t)dir << 17);
  unsigned int* fl = flags + ((dir * 2 + bg) << 6);
  const int arow = bg * 32 + mi * 16 + (l & 15);   // batch row (MFMA M-dim)
  const int akh = (kh << 9) + ((l >> 4) << 3);     // Whh k-offset of this lane's fragment
  const int akx = kh * (KX / 2) + ((l >> 4) << 3); // Wih k-offset
  const int wn = l & 15;
  const int wsw = (wn & 7) << 3;
  __syncthreads();
  for (int s = 0; s < 512; ++s) {
    const int t = dir ? (511 - s) : s;
    f32x4 acc = {0.f, 0.f, 0.f, 0.f};
    {  // x @ Wih^T — flag-independent
      const f16* xr = X + (((size_t)(t * 64 + arow)) << XSH) + akx;
#pragma unroll
      for (int it = 0; it < KX / 64; ++it) {
        f16x8 av = *(const f16x8*)(xr + it * 32);
        const int ko = akx + it * 32;
        f16x8 bv = *(const f16x8*)&Wi[(wn << XSH) + (ko ^ wsw)];
        acc = __builtin_amdgcn_mfma_f32_16x16x32_f16(av, bv, acc, 0, 0, 0);
      }
    }
    if (s > 0) {
      const unsigned int tgt = (unsigned int)(LAYER * 512 + s);
      unsigned int* fp = fl + l;  // lane <-> cg flag
      for (;;) {
        unsigned int f = __hip_atomic_load(fp, __ATOMIC_RELAXED, __HIP_MEMORY_SCOPE_AGENT);
        if (__all((int)(f >= tgt))) break;
      }
      __threadfence();  // acquire
      const f16* hrow = hD + (((size_t)(s & 1)) << 16) + (((size_t)arow) << 10) + akh;
#pragma unroll
      for (int it = 0; it < 16; ++it) {
        f16x8 av = *(const f16x8*)(hrow + it * 32);
        const int ko = akh + it * 32;
        f16x8 bv = *(const f16x8*)&Wl[(wn << 10) + (ko ^ wsw)];
        acc = __builtin_amdgcn_mfma_f32_16x16x32_f16(av, bv, acc, 0, 0, 0);
      }
    }
    if (kh == 1) {
#pragma unroll
      for (int r = 0; r < 4; ++r) part[mi][((l >> 4) << 2) + r][l & 15] = acc[r];
    }
    __syncthreads();
    if (kh == 0) {
#pragma unroll
      for (int r = 0; r < 4; ++r) {
        const int row = ((l >> 4) << 2) + r;
        const int b_ = bg * 32 + mi * 16 + row;
        const int n = cg * 16 + (l & 15);
        float v = acc[r] + part[mi][row][l & 15] + bn;
        v = tanhf(v);
        hD[(((size_t)((s + 1) & 1)) << 16) + (((size_t)b_) << 10) + n] = (f16)v;
        if (LAYER == 0)
          seqout[(((size_t)(t * 64 + b_)) << 11) + (dir << 10) + n] = (f16)v;
        if (s == 511)
          dout[(((size_t)(ld * 64 + b_)) << 10) + n] = v;
      }
    }
    __syncthreads();
    if (tid == 0) {
      __threadfence();  // release: h stores visible before flag
      __hip_atomic_store(&fl[cg], (unsigned int)(LAYER * 512 + s + 1),
                         __ATOMIC_RELEASE, __HIP_MEMORY_SCOPE_AGENT);
    }
  }
}

// ---------------- launch ----------------

extern "C" void kernel_launch(void* const* d_in, const int* in_sizes, int n_in,
                              void* d_out, int out_size, void* d_ws, size_t ws_size,
                              hipStream_t stream) {
  const int* src    = (const int*)d_in[0];
  const float* emb  = (const float*)d_in[1];
  const float* W1   = (const float*)d_in[2];
  const float* b1   = (const float*)d_in[3];
  const float* W2   = (const float*)d_in[4];
  const float* b2   = (const float*)d_in[5];
  const float* Wih0 = (const float*)d_in[6];
  const float* WihL = (const float*)d_in[7];
  const float* Whh  = (const float*)d_in[8];
  const float* bih  = (const float*)d_in[9];
  const float* bhh  = (const float*)d_in[10];
  float* out = (float*)d_out;
  char* ws = (char*)d_ws;

  if (ws_size < WS_NEED) {  // diagnostic fallback: clean absmax-fail instead of OOB fault
    zero_k<<<(out_size + 255) / 256, 256, 0, stream>>>((unsigned int*)d_out, out_size);
    return;
  }

  f16* X0   = (f16*)(ws + OFF_X0);
  f16* X1   = (f16*)(ws + OFF_X1);
  f16* EMB  = (f16*)(ws + OFF_EMB);
  f16* MLP1 = (f16*)(ws + OFF_MLP1);
  f16* HB   = (f16*)(ws + OFF_H);
  unsigned int* FLAGS = (unsigned int*)(ws + OFF_FLAGS);
  float* BIAS = (float*)(ws + OFF_BIAS);
  f16* W1C  = (f16*)(ws + OFF_W1C);
  f16* W2C  = (f16*)(ws + OFF_W2C);

  cvt_k<<<256, 256, 0, stream>>>(W1, W1C, 131072);
  cvt_k<<<256, 256, 0, stream>>>(W2, W2C, 262144);
  bias_k<<<16, 256, 0, stream>>>(bih, bhh, BIAS);
  zero_k<<<1, 256, 0, stream>>>(FLAGS, 256);

  embed_k<<<32768, 128, 0, stream>>>(src, emb, EMB);
  gemm_f16<1><<<2048, 256, 0, stream>>>(EMB, 512, W1C, MLP1, b1, 32768, 1024, 512);
  gemm_f16<3><<<2048, 256, 0, stream>>>(MLP1, 1024, W2C, X0, b2, 32768, 1024, 1024);

  rnn_scan<0><<<256, 256, 0, stream>>>(X0, Wih0, Whh, BIAS, HB, FLAGS, X1, out);
  rnn_scan<1><<<256, 256, 0, stream>>>(X1, WihL, Whh, BIAS, HB, FLAGS, nullptr, out);
}

// Round 3
// 7038.897 us; speedup vs baseline: 5.9323x; 5.9323x over previous
//
#include <hip/hip_runtime.h>

// RNNEncModel: embed -> MLP(relu x2) -> 2x bidirectional tanh-RNN -> final states [4,64,1024] f32.
// B=64 T=512 E=512 H=1024 V=32000.
// fp16 compute (f32 MFMA accum). Input projections FUSED into the persistent scan kernels.
// Cross-block step sync via monotonic flags; h-state exchanged through LLC with sc0/sc1
// cache-bypass accesses (NO threadfence -> no per-step L2 invalidate storm). ws NEED = 196 MB.

typedef _Float16 f16;
typedef _Float16 f16x8 __attribute__((ext_vector_type(8)));
typedef _Float16 f16x4 __attribute__((ext_vector_type(4)));
typedef float f32x4 __attribute__((ext_vector_type(4)));

static const size_t MB_ = 1024ull * 1024ull;
static const size_t OFF_X0    = 0;                      // [512*64][1024] f16 = 64MB (MLP out, [t][b][h])
static const size_t OFF_X1    = 64 * MB_;               // [512*64][2048] f16 = 128MB (layer0 out)
static const size_t OFF_EMB   = OFF_X1;                 // tmp [32768][512] f16 = 32MB
static const size_t OFF_MLP1  = 96 * MB_;               // tmp [32768][1024] f16 = 64MB
static const size_t OFF_H     = 192 * MB_;              // [2dir][2buf][64][1024] f16 = 512KB
static const size_t OFF_FLAGS = 192 * MB_ + 512 * 1024; // [2dir][2bg][64cg] u32 = 1KB
static const size_t OFF_BIAS  = 192 * MB_ + 576 * 1024; // [4][1024] f32 (b_ih + b_hh)
static const size_t OFF_W1C   = 193 * MB_;              // W1 f16 [1024][512] = 1MB
static const size_t OFF_W2C   = 194 * MB_;              // W2 f16 [1024][1024] = 2MB
static const size_t WS_NEED   = 196 * MB_;

__device__ __forceinline__ void gld16(const void* g, void* l) {
#if __has_builtin(__builtin_amdgcn_global_load_lds)
  __builtin_amdgcn_global_load_lds((const __attribute__((address_space(1))) void*)g,
                                   (__attribute__((address_space(3))) void*)l, 16, 0, 0);
#else
  *(f16x8*)l = *(const f16x8*)g;
#endif
}

// system-coherent (LLC) 16B load: bypasses L1/L2 so cross-XCD h-state is seen without fences.
// NOTE: caller must s_waitcnt vmcnt(0) + sched_barrier before consuming the result.
__device__ __forceinline__ void llc_load16(const f16* p, f16x8& r) {
  asm volatile("global_load_dwordx4 %0, %1, off sc0 sc1" : "=&v"(r) : "v"(p));
}
// system-coherent 2B store (write-through to LLC).
__device__ __forceinline__ void llc_store2(f16* p, f16 v) {
  unsigned int b = (unsigned int)__builtin_bit_cast(unsigned short, v);
  asm volatile("global_store_short %0, %1, off sc0 sc1" :: "v"(p), "v"(b) : "memory");
}

// ---------------- utility kernels ----------------

__global__ void zero_k(unsigned int* __restrict__ p, int n) {
  int i = blockIdx.x * blockDim.x + threadIdx.x;
  if (i < n) p[i] = 0u;
}

__global__ void cvt_k(const float* __restrict__ in, f16* __restrict__ out, int n4) {
  int i = blockIdx.x * blockDim.x + threadIdx.x;
  int stride = gridDim.x * blockDim.x;
  for (; i < n4; i += stride) {
    float4 v = ((const float4*)in)[i];
    f16x4 o = {(f16)v.x, (f16)v.y, (f16)v.z, (f16)v.w};
    ((f16x4*)out)[i] = o;
  }
}

__global__ void bias_k(const float* __restrict__ a, const float* __restrict__ b, float* __restrict__ o) {
  int i = blockIdx.x * blockDim.x + threadIdx.x;
  if (i < 4096) o[i] = a[i] + b[i];
}

// embedding gather + f16 convert; padding_idx=0 -> zero row
__global__ void embed_k(const int* __restrict__ src, const float* __restrict__ tab, f16* __restrict__ out) {
  int m = blockIdx.x;     // token index b*512 + t
  int tid = threadIdx.x;  // 128 threads x 4 floats
  int tok = src[m];
  f16x4 o = {(f16)0.f, (f16)0.f, (f16)0.f, (f16)0.f};
  if (tok != 0) {
    float4 v = *(const float4*)(tab + (size_t)tok * 512 + tid * 4);
    o[0] = (f16)v.x; o[1] = (f16)v.y; o[2] = (f16)v.z; o[3] = (f16)v.w;
  }
  *(f16x4*)(out + (size_t)m * 512 + tid * 4) = o;
}

// ---------------- GEMM: C[M,N] = A[M,K(lda)] * Bw[N,K]^T ----------------
// EPI bit0: relu(acc + bias[col]); EPI bit1: scatter row=(b*512+t) -> out[(t*64+b)*1024+col] (N==1024)
template <int EPI>
__global__ __launch_bounds__(256) void gemm_f16(
    const f16* __restrict__ A, int lda, const f16* __restrict__ Bw,
    f16* __restrict__ out, const float* __restrict__ bias, int M, int N, int K) {
  __shared__ alignas(16) f16 As[4096];  // [128][32]
  __shared__ alignas(16) f16 Bs[4096];  // [128][32]
  const int nt = N >> 7;
  const int bx = blockIdx.x;
  const int tm = bx / nt, tn = bx - tm * nt;
  const int tid = threadIdx.x;
  const int l = tid & 63, w = tid >> 6;
  const int wr = w >> 1, wc = w & 1;
  const int srow = (w << 4) + (l >> 2);
  const int scol = (l & 3) << 3;
  const f16* Ab = A + (size_t)(tm * 128 + srow) * lda + scol;
  const f16* Bb = Bw + (size_t)(tn * 128 + srow) * K + scol;
  f32x4 acc[4][4];
#pragma unroll
  for (int i = 0; i < 4; i++)
#pragma unroll
    for (int j = 0; j < 4; j++) acc[i][j] = (f32x4){0.f, 0.f, 0.f, 0.f};
  const int ar = l & 15, ak = (l >> 4) << 3;
  for (int k0 = 0; k0 < K; k0 += 32) {
    gld16(Ab + k0, &As[tid * 8]);
    gld16(Ab + (size_t)64 * lda + k0, &As[tid * 8 + 2048]);
    gld16(Bb + k0, &Bs[tid * 8]);
    gld16(Bb + (size_t)64 * K + k0, &Bs[tid * 8 + 2048]);
    __syncthreads();
    f16x8 av[4], bv[4];
#pragma unroll
    for (int i = 0; i < 4; i++) av[i] = *(const f16x8*)&As[(wr * 64 + i * 16 + ar) * 32 + ak];
#pragma unroll
    for (int j = 0; j < 4; j++) bv[j] = *(const f16x8*)&Bs[(wc * 64 + j * 16 + ar) * 32 + ak];
#pragma unroll
    for (int i = 0; i < 4; i++)
#pragma unroll
      for (int j = 0; j < 4; j++)
        acc[i][j] = __builtin_amdgcn_mfma_f32_16x16x32_f16(av[i], bv[j], acc[i][j], 0, 0, 0);
    __syncthreads();
  }
  const int r0 = (l >> 4) << 2, c0 = l & 15;
#pragma unroll
  for (int i = 0; i < 4; i++) {
#pragma unroll
    for (int j = 0; j < 4; j++) {
      const int col = tn * 128 + wc * 64 + j * 16 + c0;
      const float bc = (EPI & 1) ? bias[col] : 0.f;
#pragma unroll
      for (int r = 0; r < 4; r++) {
        const int row = tm * 128 + wr * 64 + i * 16 + r0 + r;
        float v = acc[i][j][r];
        if (EPI & 1) { v += bc; v = v > 0.f ? v : 0.f; }
        if (EPI & 2) {
          const int b_ = row >> 9, t = row & 511;
          out[((size_t)(t * 64 + b_) << 10) + col] = (f16)v;
        } else {
          out[(size_t)row * N + col] = (f16)v;
        }
      }
    }
  }
}

// ---------------- fused recurrence ----------------
// grid 256 = dir(2) x bg(2, 32 batch rows) x cg(64, 16 cols). 4 waves: (mi batch-half, kh K-half).
// Per step: h_new = tanh(x[t]@Wih^T + h@Whh^T + bias). Wih & Whh slices f16 in LDS (XOR-swizzled).
// x-projection computed BEFORE the flag wait -> hides under sync latency.
// Sync: flags = monotonic epoch, relaxed agent atomics; h through LLC via sc0/sc1 accesses.
// NO fences -> L2 keeps X hot (the round-2 21ms/scan was per-step L2-invalidate storm).
template <int LAYER>
__global__ __launch_bounds__(256) void rnn_scan(
    const f16* __restrict__ X,       // [512*64][KX]  (t-major)
    const float* __restrict__ Wih,   // [2][1024][KX] f32
    const float* __restrict__ Whh,   // [2][2][1024][1024] f32
    const float* __restrict__ bsum,  // [4][1024]
    f16* __restrict__ hbuf,          // [2][2][64][1024] f16
    unsigned int* __restrict__ flags,// [2][2][64] u32
    f16* __restrict__ seqout,        // LAYER0: [512*64][2048]
    float* __restrict__ dout) {      // [4][64][1024]
  constexpr int KX = LAYER ? 2048 : 1024;
  constexpr int XSH = LAYER ? 11 : 10;
  const int bid = blockIdx.x;
  const int dir = bid >> 7, bg = (bid >> 6) & 1, cg = bid & 63;
  const int tid = threadIdx.x, l = tid & 63, w = tid >> 6;
  const int mi = w & 1, kh = w >> 1;
  __shared__ alignas(16) f16 Wl[16 * 1024];   // Whh slice
  __shared__ alignas(16) f16 Wi[16 * KX];     // Wih slice
  __shared__ float part[2][16][16];
  const int ld = LAYER * 2 + dir;
  // stage Whh slice (16 out-cols x 1024) f32 -> f16, XOR swizzle (k0 ^= (n&7)<<3)
  for (int ch = tid; ch < 2048; ch += 256) {
    const int n = ch >> 7, k0 = (ch & 127) << 3;
    const float* wp = Whh + (((size_t)(ld * 1024 + cg * 16 + n)) << 10) + k0;
    float4 v0 = *(const float4*)wp, v1 = *(const float4*)(wp + 4);
    f16x8 hv = {(f16)v0.x, (f16)v0.y, (f16)v0.z, (f16)v0.w,
                (f16)v1.x, (f16)v1.y, (f16)v1.z, (f16)v1.w};
    *(f16x8*)&Wl[(n << 10) + (k0 ^ ((n & 7) << 3))] = hv;
  }
  // stage Wih slice (16 out-cols x KX) f32 -> f16, same swizzle
  for (int ch = tid; ch < (16 * KX / 8); ch += 256) {
    const int n = ch >> (XSH - 3), k0 = (ch & (KX / 8 - 1)) << 3;
    const float* wp = Wih + ((size_t)(dir * 1024 + cg * 16 + n)) * KX + k0;
    float4 v0 = *(const float4*)wp, v1 = *(const float4*)(wp + 4);
    f16x8 hv = {(f16)v0.x, (f16)v0.y, (f16)v0.z, (f16)v0.w,
                (f16)v1.x, (f16)v1.y, (f16)v1.z, (f16)v1.w};
    *(f16x8*)&Wi[(n << XSH) + (k0 ^ ((n & 7) << 3))] = hv;
  }
  const float bn = bsum[(ld << 10) + cg * 16 + (l & 15)];
  f16* hD = hbuf + ((size_t)dir << 17);
  unsigned int* fl = flags + ((dir * 2 + bg) << 6);
  const int arow = bg * 32 + mi * 16 + (l & 15);   // batch row (MFMA M-dim)
  const int akh = (kh << 9) + ((l >> 4) << 3);     // Whh k-offset of this lane's fragment
  const int akx = kh * (KX / 2) + ((l >> 4) << 3); // Wih k-offset
  const int wn = l & 15;
  const int wsw = (wn & 7) << 3;
  __syncthreads();
  for (int s = 0; s < 512; ++s) {
    const int t = dir ? (511 - s) : s;
    f32x4 acc = {0.f, 0.f, 0.f, 0.f};
    {  // x @ Wih^T — flag-independent, overlaps the wait below (normal cached loads)
      const f16* xr = X + (((size_t)(t * 64 + arow)) << XSH) + akx;
#pragma unroll
      for (int it = 0; it < KX / 64; ++it) {
        f16x8 av = *(const f16x8*)(xr + it * 32);
        const int ko = akx + it * 32;
        f16x8 bv = *(const f16x8*)&Wi[(wn << XSH) + (ko ^ wsw)];
        acc = __builtin_amdgcn_mfma_f32_16x16x32_f16(av, bv, acc, 0, 0, 0);
      }
    }
    if (s > 0) {
      const unsigned int tgt = (unsigned int)(LAYER * 512 + s);
      unsigned int* fp = fl + l;  // lane <-> cg flag
      for (;;) {
        unsigned int f = __hip_atomic_load(fp, __ATOMIC_RELAXED, __HIP_MEMORY_SCOPE_AGENT);
        if (__all((int)(f >= tgt))) break;
      }
      // h state: 16 LLC loads in flight, one drain, then MFMAs (rule #18: sched_barrier)
      const f16* hrow = hD + (((size_t)(s & 1)) << 16) + (((size_t)arow) << 10) + akh;
      f16x8 hv[16];
#pragma unroll
      for (int it = 0; it < 16; ++it) llc_load16(hrow + it * 32, hv[it]);
      asm volatile("s_waitcnt vmcnt(0)" ::: "memory");
      __builtin_amdgcn_sched_barrier(0);
#pragma unroll
      for (int it = 0; it < 16; ++it) {
        const int ko = akh + it * 32;
        f16x8 bv = *(const f16x8*)&Wl[(wn << 10) + (ko ^ wsw)];
        acc = __builtin_amdgcn_mfma_f32_16x16x32_f16(hv[it], bv, acc, 0, 0, 0);
      }
    }
    if (kh == 1) {
#pragma unroll
      for (int r = 0; r < 4; ++r) part[mi][((l >> 4) << 2) + r][l & 15] = acc[r];
    }
    __syncthreads();
    if (kh == 0) {
#pragma unroll
      for (int r = 0; r < 4; ++r) {
        const int row = ((l >> 4) << 2) + r;
        const int b_ = bg * 32 + mi * 16 + row;
        const int n = cg * 16 + (l & 15);
        float v = acc[r] + part[mi][row][l & 15] + bn;
        v = tanhf(v);
        llc_store2(hD + (((size_t)((s + 1) & 1)) << 16) + (((size_t)b_) << 10) + n, (f16)v);
        if (LAYER == 0)
          seqout[(((size_t)(t * 64 + b_)) << 11) + (dir << 10) + n] = (f16)v;
        if (s == 511)
          dout[(((size_t)(ld * 64 + b_)) << 10) + n] = v;
      }
      // drain this wave's h stores (write-through to LLC) BEFORE the barrier, so tid0's
      // flag publish after the barrier implies all h stores are globally visible.
      asm volatile("s_waitcnt vmcnt(0)" ::: "memory");
    }
    __syncthreads();
    if (tid == 0) {
      __hip_atomic_store(&fl[cg], (unsigned int)(LAYER * 512 + s + 1),
                         __ATOMIC_RELAXED, __HIP_MEMORY_SCOPE_AGENT);
    }
    __builtin_amdgcn_sched_barrier(0);
  }
}

// ---------------- launch ----------------

extern "C" void kernel_launch(void* const* d_in, const int* in_sizes, int n_in,
                              void* d_out, int out_size, void* d_ws, size_t ws_size,
                              hipStream_t stream) {
  const int* src    = (const int*)d_in[0];
  const float* emb  = (const float*)d_in[1];
  const float* W1   = (const float*)d_in[2];
  const float* b1   = (const float*)d_in[3];
  const float* W2   = (const float*)d_in[4];
  const float* b2   = (const float*)d_in[5];
  const float* Wih0 = (const float*)d_in[6];
  const float* WihL = (const float*)d_in[7];
  const float* Whh  = (const float*)d_in[8];
  const float* bih  = (const float*)d_in[9];
  const float* bhh  = (const float*)d_in[10];
  float* out = (float*)d_out;
  char* ws = (char*)d_ws;

  if (ws_size < WS_NEED) {  // diagnostic fallback: clean absmax-fail instead of OOB fault
    zero_k<<<(out_size + 255) / 256, 256, 0, stream>>>((unsigned int*)d_out, out_size);
    return;
  }

  f16* X0   = (f16*)(ws + OFF_X0);
  f16* X1   = (f16*)(ws + OFF_X1);
  f16* EMB  = (f16*)(ws + OFF_EMB);
  f16* MLP1 = (f16*)(ws + OFF_MLP1);
  f16* HB   = (f16*)(ws + OFF_H);
  unsigned int* FLAGS = (unsigned int*)(ws + OFF_FLAGS);
  float* BIAS = (float*)(ws + OFF_BIAS);
  f16* W1C  = (f16*)(ws + OFF_W1C);
  f16* W2C  = (f16*)(ws + OFF_W2C);

  cvt_k<<<256, 256, 0, stream>>>(W1, W1C, 131072);
  cvt_k<<<256, 256, 0, stream>>>(W2, W2C, 262144);
  bias_k<<<16, 256, 0, stream>>>(bih, bhh, BIAS);
  zero_k<<<1, 256, 0, stream>>>(FLAGS, 256);

  embed_k<<<32768, 128, 0, stream>>>(src, emb, EMB);
  gemm_f16<1><<<2048, 256, 0, stream>>>(EMB, 512, W1C, MLP1, b1, 32768, 1024, 512);
  gemm_f16<3><<<2048, 256, 0, stream>>>(MLP1, 1024, W2C, X0, b2, 32768, 1024, 1024);

  rnn_scan<0><<<256, 256, 0, stream>>>(X0, Wih0, Whh, BIAS, HB, FLAGS, X1, out);
  rnn_scan<1><<<256, 256, 0, stream>>>(X1, WihL, Whh, BIAS, HB, FLAGS, nullptr, out);
}